// Round 23
// baseline (187.196 us; speedup 1.0000x reference)
//
#include <hip/hip_runtime.h>
#include <math.h>

#define NB 4
#define J 4096
#define KDIM 8192
#define DDIM 64
#define DD 64
#define TOPK 64

#define BM 32
#define THREADS 512
#define THREADS_SEL 256
#define NITER_H 16            // per half: 16 iters * (8 waves * 32 cols) = 4096 cols
#define CAP_H 128             // candidate capacity per row PER COLUMN-HALF
#define GCAP 256              // global candidate slots per row (2 halves)
#define OVFCAP 262144

// dense route pipeline: routes[row][64] -> LDS bins -> group lists -> k-sorted
#define KG 128                // columns per group
#define NGRP (KDIM / KG)      // 64 groups per batch
#define GLCAP 8192            // per-(b,group) list capacity (mean 4096)
#define BINROWS 16            // rows per binning block
#define BINCAP 96             // per-bin LDS capacity (mean 16)
#define CH 128                // gather task size (entries)
#define MAXTASK 40960         // hard bound: 32768 nonzero (b,k) + 1M/128
// zeroed control region (rcnt+flags+ovf pad+gcnt+glcnt), bytes (16-divisible)
#define ZBYTES ((size_t)NB * J * 4 + (size_t)NB * J * 4 + 256 + \
                (size_t)NB * J * 2 * 4 + (size_t)NB * NGRP * 4)

typedef _Float16 half8_t __attribute__((ext_vector_type(8)));
typedef float f32x16 __attribute__((ext_vector_type(16)));
union H8 { half8_t h; uint4 u; };
__device__ __forceinline__ half8_t as_h8(uint4 v) { H8 x; x.u = v; return x.h; }

__device__ __forceinline__ unsigned f2key(float f) {
  unsigned u = __float_as_uint(f);
  return u ^ (unsigned)(((int)u >> 31) | 0x80000000);
}
__device__ __forceinline__ float key2f(unsigned k) {
  unsigned u = (k & 0x80000000u) ? (k & 0x7FFFFFFFu) : ~k;
  return __uint_as_float(u);
}
__device__ __forceinline__ unsigned wred_maxu(unsigned v) {
  #pragma unroll
  for (int o = 32; o > 0; o >>= 1) { unsigned u = __shfl_xor(v, o, 64); v = u > v ? u : v; }
  return v;
}
__device__ __forceinline__ unsigned wred_minu(unsigned v) {
  #pragma unroll
  for (int o = 32; o > 0; o >>= 1) { unsigned u = __shfl_xor(v, o, 64); v = u < v ? u : v; }
  return v;
}
__device__ __forceinline__ float wred_addf(float v) {
  #pragma unroll
  for (int o = 32; o > 0; o >>= 1) v += __shfl_xor(v, o, 64);
  return v;
}

// ---------------------------------------------------------------------------
// K0: W_route -> f16 B-fragments (WFh) + fp32 transpose (WT) ; blocks past
// KDIM/64 copy dst -> out AND zero the control region (folded init + memset).
// ---------------------------------------------------------------------------
__global__ void k_prep(const float* __restrict__ W, unsigned* __restrict__ WFh,
                       float* __restrict__ WT,
                       const float* __restrict__ dst_state,
                       const float* __restrict__ dst_val,
                       float* __restrict__ out_state, float* __restrict__ out_val,
                       uint4* __restrict__ zbase)
{
  if (blockIdx.x >= KDIM / 64) {
    const unsigned bid2 = blockIdx.x - KDIM / 64;   // 0..1023
    const size_t i = (size_t)bid2 * 256 + threadIdx.x;
    const size_t stride = (size_t)1024 * 256;
    const size_t nS = (size_t)NB * KDIM;
    const size_t nV4 = (size_t)NB * KDIM * DD / 4;
    const size_t nZ4 = ZBYTES / 16;
    for (size_t q = i; q < nZ4; q += stride)
      zbase[q] = make_uint4(0u, 0u, 0u, 0u);
    for (size_t q = i; q < nV4; q += stride)
      ((float4*)out_val)[q] = ((const float4*)dst_val)[q];
    for (size_t q = i; q < nS; q += stride)
      out_state[q] = dst_state[q];
    return;
  }
  __shared__ _Float16 lh[64][64];  // [col][d]
  __shared__ float lf[64][64];
  const int t = threadIdx.x;
  const int kb = blockIdx.x * 64;
  for (int i = t; i < 4096; i += 256) {
    const int d = i >> 6, c = i & 63;
    const float x = W[(size_t)d * KDIM + kb + c];
    lh[c][d] = (_Float16)x;
    lf[c][d] = x;
  }
  __syncthreads();
  for (int q = t; q < 512; q += 256) {
    const int gt2 = q >> 8, rem = q & 255;
    const int ks = rem >> 6, lane = rem & 63;
    const int c = gt2 * 32 + (lane & 31);
    const int d0 = ks * 16 + (lane >> 5) * 8;
    const int gtile = blockIdx.x * 2 + gt2;
    const size_t off = ((size_t)(gtile * 4 + ks) * 64 + lane) * 4;  // dwords
    *(uint4*)(WFh + off) = *(const uint4*)&lh[c][d0];
  }
  for (int q = t; q < 1024; q += 256) {
    const int c = q >> 4, d0 = (q & 15) * 4;
    *(float4*)(WT + (size_t)(kb + c) * DDIM + d0) = *(const float4*)&lf[c][d0];
  }
}

// ---------------------------------------------------------------------------
// K1a: fast pass, split over column halves (blockIdx.y = h in {0,1}).
// R16 single-acc shape (40 VGPR + 16 AGPR). R21: s_setprio(1) around the
// MFMA cluster (T5; measured -1us). R23: pv epilogue split across BOTH
// halves (h gives pv col half) -- removes the h==1 tail imbalance.
// launch_bounds min-waves stays 4 (R2/R3).
// ---------------------------------------------------------------------------
__global__ __launch_bounds__(THREADS, 4) void k_cand(
    const float* __restrict__ val, const unsigned* __restrict__ WFh,
    const float* __restrict__ W_val, float* __restrict__ pv,
    unsigned short* __restrict__ gidx, unsigned* __restrict__ gcnt,
    float* __restrict__ gtau, unsigned* __restrict__ flags)
{
  __shared__ __align__(16) float val_lds[BM][DDIM + 4];
  __shared__ unsigned short cand_idx[BM][CAP_H];
  __shared__ unsigned have[BM];
  __shared__ float tauF[BM];

  const int t = threadIdx.x;
  const int lane = t & 63;
  const int wv = t >> 6;                // 0..7
  const int hi = lane >> 5;
  const int lane31 = lane & 31;
  const int row0 = blockIdx.x * BM;
  const int h = blockIdx.y;             // column half

  {  // stage val rows (coalesced float4)
    const int r = t >> 4, d0 = (t & 15) * 4;
    const float4 v4 = *(const float4*)(val + (size_t)(row0 + r) * DDIM + d0);
    val_lds[r][d0] = v4.x; val_lds[r][d0 + 1] = v4.y;
    val_lds[r][d0 + 2] = v4.z; val_lds[r][d0 + 3] = v4.w;
  }
  __syncthreads();

  // tau (margined): logits | val_row ~ iid N(0, sigma^2), sigma = ||val||/8.
  if (t < BM) {
    float n2 = 0.f;
    #pragma unroll
    for (int d = 0; d < DDIM; ++d) { const float x = val_lds[t][d]; n2 = fmaf(x, x, n2); }
    tauF[t] = 0.26f * sqrtf(n2);  // 2.08/8 * ||val||
    have[t] = 0u;
    if (h == 0) gtau[row0 + t] = tauF[t];
  }

  // A fragments (f16)
  half8_t ah[4];
  {
    const int m = lane31;
    #pragma unroll
    for (int ks = 0; ks < 4; ++ks) {
      const int d0 = ks * 16 + hi * 8;
      #pragma unroll
      for (int j = 0; j < 8; ++j) ah[ks][j] = (_Float16)val_lds[m][d0 + j];
    }
  }
  __syncthreads();  // tau ready

  float taufr[16];
  #pragma unroll
  for (int r = 0; r < 16; ++r) taufr[r] = tauF[(r & 3) + 8 * (r >> 2) + 4 * hi];

  // ============== FAST PASS: pipelined loads, no barriers ==================
  const unsigned* wpBase = WFh + (size_t)(h * 128 + wv) * 1024 + lane * 4;  // dwords
  const unsigned* wp = wpBase;
  uint4 b0 = *(const uint4*)(wp);        uint4 b1 = *(const uint4*)(wp + 256);
  uint4 b2 = *(const uint4*)(wp + 512);  uint4 b3 = *(const uint4*)(wp + 768);

  #pragma unroll 1
  for (int it = 0; it < NITER_H; ++it) {
    f32x16 acc0;
    #pragma unroll
    for (int i = 0; i < 16; ++i) acc0[i] = 0.f;
    __builtin_amdgcn_s_setprio(1);
    acc0 = __builtin_amdgcn_mfma_f32_32x32x16_f16(ah[0], as_h8(b0), acc0, 0, 0, 0);
    acc0 = __builtin_amdgcn_mfma_f32_32x32x16_f16(ah[1], as_h8(b1), acc0, 0, 0, 0);
    acc0 = __builtin_amdgcn_mfma_f32_32x32x16_f16(ah[2], as_h8(b2), acc0, 0, 0, 0);
    acc0 = __builtin_amdgcn_mfma_f32_32x32x16_f16(ah[3], as_h8(b3), acc0, 0, 0, 0);
    __builtin_amdgcn_s_setprio(0);

    const unsigned colbase = (unsigned)((h * 128 + it * 8 + wv) * 32 + lane31);

    // prefetch next tile; L2 latency hides under selection
    wp = (it == NITER_H - 1) ? wpBase : wp + 8192;
    b0 = *(const uint4*)(wp);        b1 = *(const uint4*)(wp + 256);
    b2 = *(const uint4*)(wp + 512);  b3 = *(const uint4*)(wp + 768);

    #pragma unroll
    for (int r = 0; r < 16; ++r) {
      const int row = (r & 3) + 8 * (r >> 2) + 4 * hi;
      if (acc0[r] > taufr[r]) {
        const unsigned slot = atomicAdd(&have[row], 1u);
        if (slot < CAP_H) cand_idx[row][slot] = (unsigned short)colbase;
      }
    }
  }

  // ---- pv = val @ W_val ---- (R23: split across halves; h = col half) ----
  {
    const int r = t >> 4, e0 = (t & 15) * 2 + h * 32;
    float a0 = 0.f, a1 = 0.f;
    #pragma unroll 8
    for (int d = 0; d < DDIM; ++d) {
      const float v = val_lds[r][d];
      const float2 w2 = *(const float2*)(W_val + (size_t)d * DD + e0);
      a0 = fmaf(v, w2.x, a0); a1 = fmaf(v, w2.y, a1);
    }
    *(float2*)(pv + (size_t)(row0 + r) * DD + e0) = make_float2(a0, a1);
  }

  __syncthreads();  // have[] + cand_idx final

  // ---- flush candidates to global (coalesced u16 runs per row) ----
  for (int i = t; i < BM * CAP_H; i += THREADS) {
    const int r = i >> 7, s = i & (CAP_H - 1);
    const unsigned hv = have[r];
    const int lim = hv < CAP_H ? (int)hv : CAP_H;
    if (s < lim)
      gidx[(size_t)(row0 + r) * GCAP + h * CAP_H + s] = cand_idx[r][s];
  }
  if (t < BM) {
    const unsigned hv = have[t];
    gcnt[(size_t)(row0 + t) * 2 + h] = hv < CAP_H ? hv : CAP_H;
    if (hv > CAP_H) flags[row0 + t] = 1u;  // incomplete -> fix phase in k_bin
  }
}

// ---------------------------------------------------------------------------
// K1b: per-row selection, one wave per row. ILP-2 exact recompute (R7/R16
// measured optimum), ballot binary-search top-64, softmax, DENSE per-row
// route write. R22: setprio(1) around the reduce burst (T5; measured -1us).
// ---------------------------------------------------------------------------
__global__ __launch_bounds__(THREADS_SEL, 4) void k_select(
    const float* __restrict__ val, const float* __restrict__ state,
    const float* __restrict__ WT,
    const unsigned short* __restrict__ gidx, const unsigned* __restrict__ gcnt,
    const float* __restrict__ gtau, unsigned* __restrict__ flags,
    uint2* __restrict__ routes, unsigned* __restrict__ rcnt)
{
  __shared__ float skey[THREADS_SEL / 64][GCAP];  // per-wave exact-key scratch
  const int t = threadIdx.x;
  const int lane = t & 63;
  const int wv = t >> 6;
  const int row = blockIdx.x * (THREADS_SEL / 64) + wv;

  if (flags[row]) return;                 // incomplete candidates -> fix phase
  const int c0 = (int)gcnt[(size_t)row * 2];
  const int c1 = (int)gcnt[(size_t)row * 2 + 1];
  const int nc = c0 + c1;
  if (nc < TOPK) { if (lane == 0) flags[row] = 1u; return; }
  const float tau = gtau[row];

  // ---- exact fp32 keys: quad-cooperative, line-cooperative, ILP-2 ----
  const int cq = lane >> 2;   // candidate sub-slot within group: 0..15
  const int dq = lane & 3;    // quad sub-lane: 16B segment within each line
  float4 v4[4];
  #pragma unroll
  for (int j = 0; j < 4; ++j)
    v4[j] = *(const float4*)(val + (size_t)row * DDIM + j * 16 + dq * 4);

  const unsigned short* grow = gidx + (size_t)row * GCAP;

  unsigned id4[4];
  #pragma unroll
  for (int i = 0; i < 4; ++i) {
    const int s = i * 64 + lane;
    id4[i] = 0xFFFFFFFFu;
    if (s < nc) {
      const int ps = s < c0 ? s : (s - c0 + CAP_H);
      id4[i] = (unsigned)grow[ps];
    }
  }

  for (int s0 = 0; s0 < nc; s0 += 32) {
    const int sA = s0 + cq;
    const int sB = s0 + 16 + cq;
    const bool okA = sA < nc, okB = sB < nc;
    int psA = sA < c0 ? sA : (sA - c0 + CAP_H); if (!okA) psA = 0;
    int psB = sB < c0 ? sB : (sB - c0 + CAP_H); if (!okB) psB = 0;
    const unsigned kkA = (unsigned)grow[psA] & (KDIM - 1);
    const unsigned kkB = (unsigned)grow[psB] & (KDIM - 1);
    const float* wtA = WT + (size_t)kkA * DDIM + dq * 4;
    const float* wtB = WT + (size_t)kkB * DDIM + dq * 4;
    float4 wA[4], wB[4];
    #pragma unroll
    for (int j = 0; j < 4; ++j) wA[j] = *(const float4*)(wtA + j * 16);
    #pragma unroll
    for (int j = 0; j < 4; ++j) wB[j] = *(const float4*)(wtB + j * 16);
    float aA = 0.f, aB = 0.f;
    __builtin_amdgcn_s_setprio(1);
    #pragma unroll
    for (int j = 0; j < 4; ++j) {
      aA = fmaf(v4[j].x, wA[j].x, aA); aA = fmaf(v4[j].y, wA[j].y, aA);
      aA = fmaf(v4[j].z, wA[j].z, aA); aA = fmaf(v4[j].w, wA[j].w, aA);
      aB = fmaf(v4[j].x, wB[j].x, aB); aB = fmaf(v4[j].y, wB[j].y, aB);
      aB = fmaf(v4[j].z, wB[j].z, aB); aB = fmaf(v4[j].w, wB[j].w, aB);
    }
    aA += __shfl_xor(aA, 1, 64); aA += __shfl_xor(aA, 2, 64);
    aB += __shfl_xor(aB, 1, 64); aB += __shfl_xor(aB, 2, 64);
    __builtin_amdgcn_s_setprio(0);
    if (dq == 0) {
      if (okA) skey[wv][sA] = aA;
      if (okB) skey[wv][sB] = aB;
    }
  }
  asm volatile("s_waitcnt lgkmcnt(0)" ::: "memory");
  __builtin_amdgcn_sched_barrier(0);

  // ---- top-64 via ballot binary search, softmax ----
  unsigned k4[4];
  #pragma unroll
  for (int i = 0; i < 4; ++i) {
    const int s = i * 64 + lane;
    k4[i] = (s < nc) ? f2key(skey[wv][s]) : 0u;
  }
  unsigned lmax = k4[0];
  #pragma unroll
  for (int i = 1; i < 4; ++i) lmax = k4[i] > lmax ? k4[i] : lmax;
  const unsigned kmaxAll = wred_maxu(lmax);
  unsigned klo = f2key(0.99f * tau); if (klo == 0u) klo = 1u;
  unsigned khi = kmaxAll + 1u;
  auto cge4 = [&](unsigned th) {
    int c = 0;
    #pragma unroll
    for (int i = 0; i < 4; ++i) c += __popcll(__ballot(k4[i] >= th));
    return c;
  };
  int cnt = nc;
  while (cnt != TOPK && khi - klo > 1u) {
    const unsigned mid = klo + ((khi - klo) >> 1);
    const int c = cge4(mid);
    if (c >= TOPK) { klo = mid; cnt = c; } else khi = mid;
  }
  const unsigned thr = klo;
  if (key2f(thr) <= 1.006f * tau) {   // completeness certificate
    if (lane == 0) flags[row] = 1u;
    return;
  }
  unsigned selmask = 0u;
  if (cnt == TOPK) {
    #pragma unroll
    for (int i = 0; i < 4; ++i) if (k4[i] >= thr) selmask |= 1u << i;
  } else {
    #pragma unroll
    for (int i = 0; i < 4; ++i) if (k4[i] > thr) selmask |= 1u << i;
    int tot = 0;
    #pragma unroll
    for (int i = 0; i < 4; ++i) tot += __popcll(__ballot((selmask >> i) & 1));
    int need = TOPK - tot;
    while (need > 0) {
      unsigned best = 0xFFFFFFFFu; int bi = -1;
      #pragma unroll
      for (int i = 0; i < 4; ++i)
        if (k4[i] == thr && !(selmask & (1u << i)) && id4[i] < best) { best = id4[i]; bi = i; }
      const unsigned g = wred_minu(best);
      if (g == 0xFFFFFFFFu) break;
      if (bi >= 0 && best == g) selmask |= 1u << bi;
      --need;
    }
  }
  const float m = key2f(kmaxAll);
  float p[4]; float lsum = 0.f;
  #pragma unroll
  for (int i = 0; i < 4; ++i) {
    p[i] = 0.f;
    if (selmask & (1u << i)) { p[i] = __expf(key2f(k4[i]) - m); lsum += p[i]; }
  }
  lsum = wred_addf(lsum);
  const float st = state[row];
  const float sender = st > 20.f ? st : log1pf(__expf(st));
  const float scale = sender / lsum;
  const unsigned jloc = (unsigned)(row & (J - 1));

  // ---- dense compacted route write (no atomics, 512B/row contiguous) ----
  uint2* rrow = routes + (size_t)row * 64;
  int pre = 0;
  #pragma unroll
  for (int i = 0; i < 4; ++i) {
    const bool sel = (selmask >> i) & 1;
    const unsigned long long mball = __ballot(sel);
    const int off = pre + __popcll(mball & ((1ull << lane) - 1ull));
    if (sel)
      rrow[off] = make_uint2(__float_as_uint(p[i] * scale),
                             (id4[i] << 12) | jloc);
    pre += __popcll(mball);
  }
  if (lane == 0) rcnt[row] = (unsigned)pre;
}

// ---------------------------------------------------------------------------
// K2b: binning, with FOLDED exactness net (former k_fix). Pre-phase fixes
// flagged rows in-place (scratch aliased into bins LDS), then binning with
// ONE contiguous chunk flush per bin (single producer; R8 lesson).
// ---------------------------------------------------------------------------
__global__ __launch_bounds__(256, 2) void k_bin(
    const float* __restrict__ val, const float* __restrict__ state,
    const float* __restrict__ W, const unsigned* __restrict__ flags,
    uint2* __restrict__ routes, unsigned* __restrict__ rcnt,
    unsigned* __restrict__ glcnt, uint2* __restrict__ glist,
    unsigned* __restrict__ ovf_cnt, uint2* __restrict__ ovf)
{
  __shared__ uint2 bins[NGRP][BINCAP];   // 64*96*8 = 48KB
  __shared__ unsigned bcnt[NGRP];
  __shared__ unsigned bbase[NGRP];
  __shared__ unsigned anyf;
  const int t = threadIdx.x;
  const int lane = t & 63;
  const int wv = t >> 6;
  const int row0 = blockIdx.x * BINROWS;
  const int b = row0 / J;

  // ---- folded k_fix pre-phase (rare; scratch aliases bins LDS) ----
  if (t == 0) anyf = 0u;
  __syncthreads();
  if (t < BINROWS && flags[row0 + t]) anyf = 1u;
  __syncthreads();
  if (anyf) {
    unsigned* lsk = (unsigned*)bins;                          // [16][TOPK+1]
    unsigned short* lsi = (unsigned short*)(lsk + BINROWS * (TOPK + 1));
    float* lv = (float*)(lsi + BINROWS * TOPK);               // [16][DDIM]
    if (t < BINROWS && flags[row0 + t]) {
      const int row = row0 + t;
      unsigned* mk = lsk + t * (TOPK + 1);
      unsigned short* mi = lsi + t * TOPK;
      float* mv = lv + t * DDIM;
      for (int d = 0; d < DDIM; ++d) mv[d] = val[(size_t)row * DDIM + d];
      int m = 0, worst = 0;
      for (int k = 0; k < KDIM; ++k) {
        float acc = 0.f;
        #pragma unroll 8
        for (int d = 0; d < DDIM; ++d) acc = fmaf(mv[d], W[(size_t)d * KDIM + k], acc);
        const unsigned key = f2key(acc);
        if (m < TOPK) {
          mk[m] = key; mi[m] = (unsigned short)k; ++m;
          if (m == TOPK) {
            worst = 0;
            for (int q = 1; q < TOPK; ++q)
              if (mk[q] < mk[worst] ||
                  (mk[q] == mk[worst] && mi[q] > mi[worst])) worst = q;
          }
        } else if (key > mk[worst]) {  // tie -> keep earlier index
          mk[worst] = key; mi[worst] = (unsigned short)k;
          worst = 0;
          for (int q = 1; q < TOPK; ++q)
            if (mk[q] < mk[worst] ||
                (mk[q] == mk[worst] && mi[q] > mi[worst])) worst = q;
        }
      }
      unsigned km = mk[0];
      for (int q = 1; q < TOPK; ++q) if (mk[q] > km) km = mk[q];
      const float mx = key2f(km);
      float lsum = 0.f;
      for (int q = 0; q < TOPK; ++q) lsum += __expf(key2f(mk[q]) - mx);
      const float st = state[row];
      const float sender = st > 20.f ? st : log1pf(__expf(st));
      const float scale = sender / lsum;
      const unsigned jloc = (unsigned)(row & (J - 1));
      uint2* rrow = routes + (size_t)row * 64;
      for (int q = 0; q < TOPK; ++q) {
        const float w = __expf(key2f(mk[q]) - mx) * scale;
        rrow[q] = make_uint2(__float_as_uint(w), ((unsigned)mi[q] << 12) | jloc);
      }
      rcnt[row] = TOPK;
    }
    __syncthreads();   // routes/rcnt for fixed rows visible; bins free again
  }

  for (int i = t; i < NGRP; i += 256) bcnt[i] = 0u;
  __syncthreads();

  for (int i = t; i < BINROWS * 64; i += 256) {
    const int r = i >> 6, s = i & 63;
    unsigned n = rcnt[row0 + r]; if (n > 64u) n = 64u;
    if (s < (int)n) {
      const uint2 e = routes[(size_t)(row0 + r) * 64 + s];
      const unsigned k = e.y >> 12;
      const unsigned g = k >> 7;               // KG = 128
      const unsigned slot = atomicAdd(&bcnt[g], 1u);
      if (slot < BINCAP) bins[g][slot] = e;
      else {
        const unsigned op = atomicAdd(ovf_cnt, 1u);
        if (op < (unsigned)OVFCAP)
          ovf[op] = make_uint2(e.x, (((unsigned)b * KDIM + k) << 12) | (e.y & (J - 1)));
      }
    }
  }
  __syncthreads();

  if (t < NGRP) {
    unsigned c = bcnt[t]; if (c > BINCAP) c = BINCAP;
    bcnt[t] = c;
    bbase[t] = c ? atomicAdd(&glcnt[b * NGRP + t], c) : 0u;
  }
  __syncthreads();

  // wave wv flushes bins [wv*16, wv*16+16), lane-parallel within each bin
  for (int g = wv * 16; g < wv * 16 + 16; ++g) {
    const unsigned c = bcnt[g];
    const unsigned base = bbase[g];
    uint2* dst = glist + (size_t)(b * NGRP + g) * GLCAP;
    for (unsigned i2 = lane; i2 < c; i2 += 64) {
      const unsigned pos = base + i2;
      const uint2 e = bins[g][i2];
      if (pos < GLCAP) dst[pos] = e;
      else {
        const unsigned k = e.y >> 12;
        const unsigned op = atomicAdd(ovf_cnt, 1u);
        if (op < (unsigned)OVFCAP)
          ovf[op] = make_uint2(e.x, (((unsigned)b * KDIM + k) << 12) | (e.y & (J - 1)));
      }
    }
  }
}

// ---------------------------------------------------------------------------
// K2c: counting sort per (b,group): glist -> glist2 segmented by k.
// Emits bounded gather tasks (bk, start, len<=CH): R12/R13 lesson -- the
// gather loop must be branchless with a FIXED k per wave, and balanced.
// ---------------------------------------------------------------------------
__global__ void k_sort(const unsigned* __restrict__ glcnt, const uint2* __restrict__ glist,
                       uint2* __restrict__ glist2, unsigned* __restrict__ ntask,
                       uint2* __restrict__ tasks)
{
  __shared__ unsigned hist[KG];
  __shared__ unsigned offs[KG];
  __shared__ unsigned cur[KG];
  const int t = threadIdx.x;
  const int b = blockIdx.x >> 6;          // NGRP = 64
  const int g = blockIdx.x & (NGRP - 1);
  unsigned n = glcnt[b * NGRP + g]; if (n > (unsigned)GLCAP) n = (unsigned)GLCAP;
  const uint2* src = glist + (size_t)(b * NGRP + g) * GLCAP;
  uint2* dst = glist2 + (size_t)(b * NGRP + g) * GLCAP;

  for (int i = t; i < KG; i += 256) hist[i] = 0u;
  __syncthreads();
  for (unsigned i = t; i < n; i += 256)
    atomicAdd(&hist[(src[i].y >> 12) & (KG - 1)], 1u);
  __syncthreads();
  // inclusive Hillis-Steele scan over 128
  if (t < KG) offs[t] = hist[t];
  __syncthreads();
  for (int d = 1; d < KG; d <<= 1) {
    unsigned v = 0u;
    if (t < KG && t >= d) v = offs[t - d];
    __syncthreads();
    if (t < KG) offs[t] += v;
    __syncthreads();
  }
  if (t < KG) {
    const unsigned h = hist[t];
    const unsigned base = offs[t] - h;      // exclusive
    cur[t] = base;
    if (h) {
      const unsigned nt = (h + CH - 1) / CH;
      unsigned tbase = atomicAdd(ntask, nt);
      const unsigned bk = (unsigned)b * KDIM + (unsigned)g * KG + (unsigned)t;
      for (unsigned s = 0; s < nt && tbase + s < (unsigned)MAXTASK; ++s) {
        const unsigned st = base + s * CH;
        unsigned ln = h - s * CH; if (ln > (unsigned)CH) ln = CH;
        tasks[tbase + s] = make_uint2(bk, st | (ln << 16));
      }
    }
  }
  __syncthreads();
  for (unsigned i = t; i < n; i += 256) {
    const uint2 e = src[i];
    const unsigned p = atomicAdd(&cur[(e.y >> 12) & (KG - 1)], 1u);
    dst[p] = e;
  }
}

// ---------------------------------------------------------------------------
// K3: gather, TASK-LIST (R7 shape): one wave per task = one k's bounded
// 128-entry sub-segment; branchless ILP-4; register acc; ONE 256B atomic
// flush (out = dst via folded init). Tail waves fold the overflow list.
// ---------------------------------------------------------------------------
__global__ void k_gather(const unsigned* __restrict__ ntask,
                         const uint2* __restrict__ tasks,
                         const uint2* __restrict__ glist2,
                         const float* __restrict__ pv, const float* __restrict__ state,
                         float* __restrict__ out_state, float* __restrict__ out_val,
                         const unsigned* __restrict__ ovf_cnt,
                         const uint2* __restrict__ ovf)
{
  const unsigned wid = ((unsigned)blockIdx.x * blockDim.x + threadIdx.x) >> 6;
  const int lane = threadIdx.x & 63;
  unsigned nt = *ntask; if (nt > (unsigned)MAXTASK) nt = (unsigned)MAXTASK;
  if (wid < nt) {
    const uint2 tk = tasks[wid];
    const unsigned bk = tk.x;
    const int b = (int)(bk >> 13);            // KDIM = 8192
    const unsigned k = bk & (KDIM - 1);
    const unsigned g = k >> 7;                // KG = 128
    const unsigned st = tk.y & 0xFFFFu;
    const unsigned n = tk.y >> 16;
    const size_t jbase = (size_t)b * J;
    const uint2* lst = glist2 + (size_t)((unsigned)b * NGRP + g) * GLCAP + st;

    float a0 = 0.f, a1 = 0.f, a2 = 0.f, a3 = 0.f;
    float s0 = 0.f, s1 = 0.f, s2 = 0.f, s3 = 0.f;
    unsigned i = 0;
    for (; i + 4 <= n; i += 4) {
      const uint2 e0 = lst[i + 0], e1 = lst[i + 1], e2 = lst[i + 2], e3 = lst[i + 3];
      const float w0 = __uint_as_float(e0.x), w1 = __uint_as_float(e1.x);
      const float w2 = __uint_as_float(e2.x), w3 = __uint_as_float(e3.x);
      const unsigned j0 = e0.y & (J - 1), j1 = e1.y & (J - 1);
      const unsigned j2 = e2.y & (J - 1), j3 = e3.y & (J - 1);
      a0 = fmaf(w0, pv[(jbase + j0) * DD + lane], a0);
      a1 = fmaf(w1, pv[(jbase + j1) * DD + lane], a1);
      a2 = fmaf(w2, pv[(jbase + j2) * DD + lane], a2);
      a3 = fmaf(w3, pv[(jbase + j3) * DD + lane], a3);
      s0 = fmaf(w0, state[jbase + j0], s0); s1 = fmaf(w1, state[jbase + j1], s1);
      s2 = fmaf(w2, state[jbase + j2], s2); s3 = fmaf(w3, state[jbase + j3], s3);
    }
    for (; i < n; ++i) {
      const uint2 e = lst[i];
      const float w = __uint_as_float(e.x);
      const unsigned j = e.y & (J - 1);
      a0 = fmaf(w, pv[(jbase + j) * DD + lane], a0);
      s0 = fmaf(w, state[jbase + j], s0);
    }
    atomicAdd(&out_val[(size_t)bk * DD + lane], (a0 + a1) + (a2 + a3));
    if (lane == 0) atomicAdd(&out_state[bk], (s0 + s1) + (s2 + s3));
  }

  // ---- overflow fold (list ~always tiny; all waves grid-stride) ----
  unsigned novf = *ovf_cnt;
  if (novf > (unsigned)OVFCAP) novf = (unsigned)OVFCAP;
  const unsigned nw = ((unsigned)gridDim.x * blockDim.x) >> 6;
  for (unsigned i = wid; i < novf; i += nw) {
    const uint2 e = ovf[i];
    const float w = __uint_as_float(e.x);
    const unsigned bk = e.y >> 12;
    const unsigned j = e.y & (J - 1);
    const size_t jg = (size_t)(bk >> 13) * J + j;
    atomicAdd(&out_val[(size_t)bk * DD + lane], w * pv[jg * DD + lane]);
    if (lane == 0) atomicAdd(&out_state[bk], w * state[jg]);
  }
}

// ---------------------------------------------------------------------------
extern "C" void kernel_launch(void* const* d_in, const int* in_sizes, int n_in,
                              void* d_out, int out_size, void* d_ws, size_t ws_size,
                              hipStream_t stream)
{
  (void)in_sizes; (void)n_in; (void)out_size; (void)ws_size;
  const float* val       = (const float*)d_in[0];
  const float* state     = (const float*)d_in[1];
  const float* dst_state = (const float*)d_in[2];
  const float* dst_val   = (const float*)d_in[3];
  const float* W_route   = (const float*)d_in[4];
  const float* W_val     = (const float*)d_in[5];
  float* out_state = (float*)d_out;
  float* out_val   = out_state + (size_t)NB * KDIM;

  char* p = (char*)d_ws;
  unsigned* rcnt    = (unsigned*)p;  p += (size_t)NB * J * 4;          // 64 KB
  unsigned* flags   = (unsigned*)p;  p += (size_t)NB * J * 4;          // 64 KB
  unsigned* ovf_cnt = (unsigned*)p;  p += 256;                         // 256 B (slot 1 = ntask)
  unsigned* gcnt    = (unsigned*)p;  p += (size_t)NB * J * 2 * 4;      // 128 KB
  unsigned* glcnt   = (unsigned*)p;  p += (size_t)NB * NGRP * 4;       // 1 KB
  uint2* tasks      = (uint2*)p;     p += (size_t)MAXTASK * 8;         // 320 KB
  float* pv         = (float*)p;     p += (size_t)NB * J * DD * 4;     // 4 MB
  unsigned* WFh     = (unsigned*)p;  p += (size_t)KDIM * DDIM * 2;     // 1 MB
  float* WT         = (float*)p;     p += (size_t)KDIM * DDIM * 4;     // 2 MB
  float* gtau       = (float*)p;     p += (size_t)NB * J * 4;          // 64 KB
  unsigned short* gidx = (unsigned short*)p;                            // 8 MB
  uint2* glist2     = (uint2*)p;     p += (size_t)NB * J * GCAP * 2;   // (alias start)
  uint2* routes     = (uint2*)p;     p += (size_t)NB * J * 64 * 8;     // 8 MB
  // glist2 (16 MB) aliases gidx+routes: both dead before k_sort runs.
  uint2* glist      = (uint2*)p;     p += (size_t)NB * NGRP * GLCAP * 8; // 16 MB
  uint2* ovf        = (uint2*)p;     p += (size_t)OVFCAP * 8;          // 2 MB
  unsigned* ntask   = ovf_cnt + 1;   // inside the zeroed 256B pad

  // control-region zeroing folded into k_prep; k_fix folded into k_bin
  hipLaunchKernelGGL(k_prep, dim3(KDIM / 64 + 1024), dim3(256), 0, stream,
                     W_route, WFh, WT, dst_state, dst_val, out_state, out_val,
                     (uint4*)rcnt);
  hipLaunchKernelGGL(k_cand, dim3(NB * J / BM, 2), dim3(THREADS), 0, stream,
                     val, WFh, W_val, pv, gidx, gcnt, gtau, flags);
  hipLaunchKernelGGL(k_select, dim3(NB * J / (THREADS_SEL / 64)), dim3(THREADS_SEL),
                     0, stream, val, state, WT, gidx, gcnt, gtau, flags,
                     routes, rcnt);
  hipLaunchKernelGGL(k_bin, dim3(NB * J / BINROWS), dim3(256), 0, stream,
                     val, state, W_route, flags, routes, rcnt,
                     glcnt, glist, ovf_cnt, ovf);
  hipLaunchKernelGGL(k_sort, dim3(NB * NGRP), dim3(256), 0, stream,
                     glcnt, glist, glist2, ntask, tasks);
  hipLaunchKernelGGL(k_gather, dim3(MAXTASK / 4), dim3(256), 0, stream,
                     ntask, tasks, glist2, pv, state, out_state, out_val,
                     ovf_cnt, ovf);
}

// Round 24
// 181.632 us; speedup vs baseline: 1.0306x; 1.0306x over previous
//
#include <hip/hip_runtime.h>
#include <math.h>

#define NB 4
#define J 4096
#define KDIM 8192
#define DDIM 64
#define DD 64
#define TOPK 64

#define BM 32
#define THREADS 512
#define THREADS_SEL 256
#define NITER_H 16            // per half: 16 iters * (8 waves * 32 cols) = 4096 cols
#define CAP_H 128             // candidate capacity per row PER COLUMN-HALF
#define GCAP 256              // global candidate slots per row (2 halves)
#define OVFCAP 262144

// dense route pipeline: routes[row][64] -> LDS bins -> group lists -> k-sorted
#define KG 128                // columns per group
#define NGRP (KDIM / KG)      // 64 groups per batch
#define GLCAP 8192            // per-(b,group) list capacity (mean 4096)
#define BINROWS 16            // rows per binning block
#define BINCAP 96             // per-bin LDS capacity (mean 16)
#define CH 128                // gather task size (entries)
#define MAXTASK 40960         // hard bound: 32768 nonzero (b,k) + 1M/128
// zeroed control region (rcnt+flags+ovf pad+gcnt+glcnt), bytes (16-divisible)
#define ZBYTES ((size_t)NB * J * 4 + (size_t)NB * J * 4 + 256 + \
                (size_t)NB * J * 2 * 4 + (size_t)NB * NGRP * 4)

typedef _Float16 half8_t __attribute__((ext_vector_type(8)));
typedef float f32x16 __attribute__((ext_vector_type(16)));
union H8 { half8_t h; uint4 u; };
__device__ __forceinline__ half8_t as_h8(uint4 v) { H8 x; x.u = v; return x.h; }

__device__ __forceinline__ unsigned f2key(float f) {
  unsigned u = __float_as_uint(f);
  return u ^ (unsigned)(((int)u >> 31) | 0x80000000);
}
__device__ __forceinline__ float key2f(unsigned k) {
  unsigned u = (k & 0x80000000u) ? (k & 0x7FFFFFFFu) : ~k;
  return __uint_as_float(u);
}
__device__ __forceinline__ unsigned wred_maxu(unsigned v) {
  #pragma unroll
  for (int o = 32; o > 0; o >>= 1) { unsigned u = __shfl_xor(v, o, 64); v = u > v ? u : v; }
  return v;
}
__device__ __forceinline__ unsigned wred_minu(unsigned v) {
  #pragma unroll
  for (int o = 32; o > 0; o >>= 1) { unsigned u = __shfl_xor(v, o, 64); v = u < v ? u : v; }
  return v;
}
__device__ __forceinline__ float wred_addf(float v) {
  #pragma unroll
  for (int o = 32; o > 0; o >>= 1) v += __shfl_xor(v, o, 64);
  return v;
}

// ---------------------------------------------------------------------------
// K0: W_route -> f16 B-fragments (WFh) + fp32 transpose (WT) ; blocks past
// KDIM/64 copy dst -> out AND zero the control region (folded init + memset).
// ---------------------------------------------------------------------------
__global__ void k_prep(const float* __restrict__ W, unsigned* __restrict__ WFh,
                       float* __restrict__ WT,
                       const float* __restrict__ dst_state,
                       const float* __restrict__ dst_val,
                       float* __restrict__ out_state, float* __restrict__ out_val,
                       uint4* __restrict__ zbase)
{
  if (blockIdx.x >= KDIM / 64) {
    const unsigned bid2 = blockIdx.x - KDIM / 64;   // 0..1023
    const size_t i = (size_t)bid2 * 256 + threadIdx.x;
    const size_t stride = (size_t)1024 * 256;
    const size_t nS = (size_t)NB * KDIM;
    const size_t nV4 = (size_t)NB * KDIM * DD / 4;
    const size_t nZ4 = ZBYTES / 16;
    for (size_t q = i; q < nZ4; q += stride)
      zbase[q] = make_uint4(0u, 0u, 0u, 0u);
    for (size_t q = i; q < nV4; q += stride)
      ((float4*)out_val)[q] = ((const float4*)dst_val)[q];
    for (size_t q = i; q < nS; q += stride)
      out_state[q] = dst_state[q];
    return;
  }
  __shared__ _Float16 lh[64][64];  // [col][d]
  __shared__ float lf[64][64];
  const int t = threadIdx.x;
  const int kb = blockIdx.x * 64;
  for (int i = t; i < 4096; i += 256) {
    const int d = i >> 6, c = i & 63;
    const float x = W[(size_t)d * KDIM + kb + c];
    lh[c][d] = (_Float16)x;
    lf[c][d] = x;
  }
  __syncthreads();
  for (int q = t; q < 512; q += 256) {
    const int gt2 = q >> 8, rem = q & 255;
    const int ks = rem >> 6, lane = rem & 63;
    const int c = gt2 * 32 + (lane & 31);
    const int d0 = ks * 16 + (lane >> 5) * 8;
    const int gtile = blockIdx.x * 2 + gt2;
    const size_t off = ((size_t)(gtile * 4 + ks) * 64 + lane) * 4;  // dwords
    *(uint4*)(WFh + off) = *(const uint4*)&lh[c][d0];
  }
  for (int q = t; q < 1024; q += 256) {
    const int c = q >> 4, d0 = (q & 15) * 4;
    *(float4*)(WT + (size_t)(kb + c) * DDIM + d0) = *(const float4*)&lf[c][d0];
  }
}

// ---------------------------------------------------------------------------
// K1a: fast pass, split over column halves (blockIdx.y = h in {0,1}).
// R16 single-acc shape (40 VGPR + 16 AGPR). R21: s_setprio(1) around the
// MFMA cluster (T5; measured -1us). pv epilogue stays h==1-only (R23's
// split DOUBLED W_val traffic with narrower loads: 52.5 -> 58.8us, reverted).
// launch_bounds min-waves stays 4 (R2/R3).
// ---------------------------------------------------------------------------
__global__ __launch_bounds__(THREADS, 4) void k_cand(
    const float* __restrict__ val, const unsigned* __restrict__ WFh,
    const float* __restrict__ W_val, float* __restrict__ pv,
    unsigned short* __restrict__ gidx, unsigned* __restrict__ gcnt,
    float* __restrict__ gtau, unsigned* __restrict__ flags)
{
  __shared__ __align__(16) float val_lds[BM][DDIM + 4];
  __shared__ unsigned short cand_idx[BM][CAP_H];
  __shared__ unsigned have[BM];
  __shared__ float tauF[BM];

  const int t = threadIdx.x;
  const int lane = t & 63;
  const int wv = t >> 6;                // 0..7
  const int hi = lane >> 5;
  const int lane31 = lane & 31;
  const int row0 = blockIdx.x * BM;
  const int h = blockIdx.y;             // column half

  {  // stage val rows (coalesced float4)
    const int r = t >> 4, d0 = (t & 15) * 4;
    const float4 v4 = *(const float4*)(val + (size_t)(row0 + r) * DDIM + d0);
    val_lds[r][d0] = v4.x; val_lds[r][d0 + 1] = v4.y;
    val_lds[r][d0 + 2] = v4.z; val_lds[r][d0 + 3] = v4.w;
  }
  __syncthreads();

  // tau (margined): logits | val_row ~ iid N(0, sigma^2), sigma = ||val||/8.
  if (t < BM) {
    float n2 = 0.f;
    #pragma unroll
    for (int d = 0; d < DDIM; ++d) { const float x = val_lds[t][d]; n2 = fmaf(x, x, n2); }
    tauF[t] = 0.26f * sqrtf(n2);  // 2.08/8 * ||val||
    have[t] = 0u;
    if (h == 0) gtau[row0 + t] = tauF[t];
  }

  // A fragments (f16)
  half8_t ah[4];
  {
    const int m = lane31;
    #pragma unroll
    for (int ks = 0; ks < 4; ++ks) {
      const int d0 = ks * 16 + hi * 8;
      #pragma unroll
      for (int j = 0; j < 8; ++j) ah[ks][j] = (_Float16)val_lds[m][d0 + j];
    }
  }
  __syncthreads();  // tau ready

  float taufr[16];
  #pragma unroll
  for (int r = 0; r < 16; ++r) taufr[r] = tauF[(r & 3) + 8 * (r >> 2) + 4 * hi];

  // ============== FAST PASS: pipelined loads, no barriers ==================
  const unsigned* wpBase = WFh + (size_t)(h * 128 + wv) * 1024 + lane * 4;  // dwords
  const unsigned* wp = wpBase;
  uint4 b0 = *(const uint4*)(wp);        uint4 b1 = *(const uint4*)(wp + 256);
  uint4 b2 = *(const uint4*)(wp + 512);  uint4 b3 = *(const uint4*)(wp + 768);

  #pragma unroll 1
  for (int it = 0; it < NITER_H; ++it) {
    f32x16 acc0;
    #pragma unroll
    for (int i = 0; i < 16; ++i) acc0[i] = 0.f;
    __builtin_amdgcn_s_setprio(1);
    acc0 = __builtin_amdgcn_mfma_f32_32x32x16_f16(ah[0], as_h8(b0), acc0, 0, 0, 0);
    acc0 = __builtin_amdgcn_mfma_f32_32x32x16_f16(ah[1], as_h8(b1), acc0, 0, 0, 0);
    acc0 = __builtin_amdgcn_mfma_f32_32x32x16_f16(ah[2], as_h8(b2), acc0, 0, 0, 0);
    acc0 = __builtin_amdgcn_mfma_f32_32x32x16_f16(ah[3], as_h8(b3), acc0, 0, 0, 0);
    __builtin_amdgcn_s_setprio(0);

    const unsigned colbase = (unsigned)((h * 128 + it * 8 + wv) * 32 + lane31);

    // prefetch next tile; L2 latency hides under selection
    wp = (it == NITER_H - 1) ? wpBase : wp + 8192;
    b0 = *(const uint4*)(wp);        b1 = *(const uint4*)(wp + 256);
    b2 = *(const uint4*)(wp + 512);  b3 = *(const uint4*)(wp + 768);

    #pragma unroll
    for (int r = 0; r < 16; ++r) {
      const int row = (r & 3) + 8 * (r >> 2) + 4 * hi;
      if (acc0[r] > taufr[r]) {
        const unsigned slot = atomicAdd(&have[row], 1u);
        if (slot < CAP_H) cand_idx[row][slot] = (unsigned short)colbase;
      }
    }
  }

  // ---- pv = val @ W_val ---- (h==1 blocks only)
  if (h == 1) {
    const int r = t >> 4, e0 = (t & 15) * 4;
    float a0 = 0.f, a1 = 0.f, a2 = 0.f, a3 = 0.f;
    #pragma unroll 8
    for (int d = 0; d < DDIM; ++d) {
      const float v = val_lds[r][d];
      const float4 w4 = *(const float4*)(W_val + (size_t)d * DD + e0);
      a0 = fmaf(v, w4.x, a0); a1 = fmaf(v, w4.y, a1);
      a2 = fmaf(v, w4.z, a2); a3 = fmaf(v, w4.w, a3);
    }
    *(float4*)(pv + (size_t)(row0 + r) * DD + e0) = make_float4(a0, a1, a2, a3);
  }

  __syncthreads();  // have[] + cand_idx final

  // ---- flush candidates to global (coalesced u16 runs per row) ----
  for (int i = t; i < BM * CAP_H; i += THREADS) {
    const int r = i >> 7, s = i & (CAP_H - 1);
    const unsigned hv = have[r];
    const int lim = hv < CAP_H ? (int)hv : CAP_H;
    if (s < lim)
      gidx[(size_t)(row0 + r) * GCAP + h * CAP_H + s] = cand_idx[r][s];
  }
  if (t < BM) {
    const unsigned hv = have[t];
    gcnt[(size_t)(row0 + t) * 2 + h] = hv < CAP_H ? hv : CAP_H;
    if (hv > CAP_H) flags[row0 + t] = 1u;  // incomplete -> fix phase in k_bin
  }
}

// ---------------------------------------------------------------------------
// K1b: per-row selection, one wave per row. ILP-2 exact recompute (R7/R16
// measured optimum), ballot binary-search top-64, softmax, DENSE per-row
// route write. R22: setprio(1) around the reduce burst (T5; measured -1us).
// ---------------------------------------------------------------------------
__global__ __launch_bounds__(THREADS_SEL, 4) void k_select(
    const float* __restrict__ val, const float* __restrict__ state,
    const float* __restrict__ WT,
    const unsigned short* __restrict__ gidx, const unsigned* __restrict__ gcnt,
    const float* __restrict__ gtau, unsigned* __restrict__ flags,
    uint2* __restrict__ routes, unsigned* __restrict__ rcnt)
{
  __shared__ float skey[THREADS_SEL / 64][GCAP];  // per-wave exact-key scratch
  const int t = threadIdx.x;
  const int lane = t & 63;
  const int wv = t >> 6;
  const int row = blockIdx.x * (THREADS_SEL / 64) + wv;

  if (flags[row]) return;                 // incomplete candidates -> fix phase
  const int c0 = (int)gcnt[(size_t)row * 2];
  const int c1 = (int)gcnt[(size_t)row * 2 + 1];
  const int nc = c0 + c1;
  if (nc < TOPK) { if (lane == 0) flags[row] = 1u; return; }
  const float tau = gtau[row];

  // ---- exact fp32 keys: quad-cooperative, line-cooperative, ILP-2 ----
  const int cq = lane >> 2;   // candidate sub-slot within group: 0..15
  const int dq = lane & 3;    // quad sub-lane: 16B segment within each line
  float4 v4[4];
  #pragma unroll
  for (int j = 0; j < 4; ++j)
    v4[j] = *(const float4*)(val + (size_t)row * DDIM + j * 16 + dq * 4);

  const unsigned short* grow = gidx + (size_t)row * GCAP;

  unsigned id4[4];
  #pragma unroll
  for (int i = 0; i < 4; ++i) {
    const int s = i * 64 + lane;
    id4[i] = 0xFFFFFFFFu;
    if (s < nc) {
      const int ps = s < c0 ? s : (s - c0 + CAP_H);
      id4[i] = (unsigned)grow[ps];
    }
  }

  for (int s0 = 0; s0 < nc; s0 += 32) {
    const int sA = s0 + cq;
    const int sB = s0 + 16 + cq;
    const bool okA = sA < nc, okB = sB < nc;
    int psA = sA < c0 ? sA : (sA - c0 + CAP_H); if (!okA) psA = 0;
    int psB = sB < c0 ? sB : (sB - c0 + CAP_H); if (!okB) psB = 0;
    const unsigned kkA = (unsigned)grow[psA] & (KDIM - 1);
    const unsigned kkB = (unsigned)grow[psB] & (KDIM - 1);
    const float* wtA = WT + (size_t)kkA * DDIM + dq * 4;
    const float* wtB = WT + (size_t)kkB * DDIM + dq * 4;
    float4 wA[4], wB[4];
    #pragma unroll
    for (int j = 0; j < 4; ++j) wA[j] = *(const float4*)(wtA + j * 16);
    #pragma unroll
    for (int j = 0; j < 4; ++j) wB[j] = *(const float4*)(wtB + j * 16);
    float aA = 0.f, aB = 0.f;
    __builtin_amdgcn_s_setprio(1);
    #pragma unroll
    for (int j = 0; j < 4; ++j) {
      aA = fmaf(v4[j].x, wA[j].x, aA); aA = fmaf(v4[j].y, wA[j].y, aA);
      aA = fmaf(v4[j].z, wA[j].z, aA); aA = fmaf(v4[j].w, wA[j].w, aA);
      aB = fmaf(v4[j].x, wB[j].x, aB); aB = fmaf(v4[j].y, wB[j].y, aB);
      aB = fmaf(v4[j].z, wB[j].z, aB); aB = fmaf(v4[j].w, wB[j].w, aB);
    }
    aA += __shfl_xor(aA, 1, 64); aA += __shfl_xor(aA, 2, 64);
    aB += __shfl_xor(aB, 1, 64); aB += __shfl_xor(aB, 2, 64);
    __builtin_amdgcn_s_setprio(0);
    if (dq == 0) {
      if (okA) skey[wv][sA] = aA;
      if (okB) skey[wv][sB] = aB;
    }
  }
  asm volatile("s_waitcnt lgkmcnt(0)" ::: "memory");
  __builtin_amdgcn_sched_barrier(0);

  // ---- top-64 via ballot binary search, softmax ----
  unsigned k4[4];
  #pragma unroll
  for (int i = 0; i < 4; ++i) {
    const int s = i * 64 + lane;
    k4[i] = (s < nc) ? f2key(skey[wv][s]) : 0u;
  }
  unsigned lmax = k4[0];
  #pragma unroll
  for (int i = 1; i < 4; ++i) lmax = k4[i] > lmax ? k4[i] : lmax;
  const unsigned kmaxAll = wred_maxu(lmax);
  unsigned klo = f2key(0.99f * tau); if (klo == 0u) klo = 1u;
  unsigned khi = kmaxAll + 1u;
  auto cge4 = [&](unsigned th) {
    int c = 0;
    #pragma unroll
    for (int i = 0; i < 4; ++i) c += __popcll(__ballot(k4[i] >= th));
    return c;
  };
  int cnt = nc;
  while (cnt != TOPK && khi - klo > 1u) {
    const unsigned mid = klo + ((khi - klo) >> 1);
    const int c = cge4(mid);
    if (c >= TOPK) { klo = mid; cnt = c; } else khi = mid;
  }
  const unsigned thr = klo;
  if (key2f(thr) <= 1.006f * tau) {   // completeness certificate
    if (lane == 0) flags[row] = 1u;
    return;
  }
  unsigned selmask = 0u;
  if (cnt == TOPK) {
    #pragma unroll
    for (int i = 0; i < 4; ++i) if (k4[i] >= thr) selmask |= 1u << i;
  } else {
    #pragma unroll
    for (int i = 0; i < 4; ++i) if (k4[i] > thr) selmask |= 1u << i;
    int tot = 0;
    #pragma unroll
    for (int i = 0; i < 4; ++i) tot += __popcll(__ballot((selmask >> i) & 1));
    int need = TOPK - tot;
    while (need > 0) {
      unsigned best = 0xFFFFFFFFu; int bi = -1;
      #pragma unroll
      for (int i = 0; i < 4; ++i)
        if (k4[i] == thr && !(selmask & (1u << i)) && id4[i] < best) { best = id4[i]; bi = i; }
      const unsigned g = wred_minu(best);
      if (g == 0xFFFFFFFFu) break;
      if (bi >= 0 && best == g) selmask |= 1u << bi;
      --need;
    }
  }
  const float m = key2f(kmaxAll);
  float p[4]; float lsum = 0.f;
  #pragma unroll
  for (int i = 0; i < 4; ++i) {
    p[i] = 0.f;
    if (selmask & (1u << i)) { p[i] = __expf(key2f(k4[i]) - m); lsum += p[i]; }
  }
  lsum = wred_addf(lsum);
  const float st = state[row];
  const float sender = st > 20.f ? st : log1pf(__expf(st));
  const float scale = sender / lsum;
  const unsigned jloc = (unsigned)(row & (J - 1));

  // ---- dense compacted route write (no atomics, 512B/row contiguous) ----
  uint2* rrow = routes + (size_t)row * 64;
  int pre = 0;
  #pragma unroll
  for (int i = 0; i < 4; ++i) {
    const bool sel = (selmask >> i) & 1;
    const unsigned long long mball = __ballot(sel);
    const int off = pre + __popcll(mball & ((1ull << lane) - 1ull));
    if (sel)
      rrow[off] = make_uint2(__float_as_uint(p[i] * scale),
                             (id4[i] << 12) | jloc);
    pre += __popcll(mball);
  }
  if (lane == 0) rcnt[row] = (unsigned)pre;
}

// ---------------------------------------------------------------------------
// K2b: binning, with FOLDED exactness net (former k_fix). Pre-phase fixes
// flagged rows in-place (scratch aliased into bins LDS), then binning with
// ONE contiguous chunk flush per bin (single producer; R8 lesson).
// ---------------------------------------------------------------------------
__global__ __launch_bounds__(256, 2) void k_bin(
    const float* __restrict__ val, const float* __restrict__ state,
    const float* __restrict__ W, const unsigned* __restrict__ flags,
    uint2* __restrict__ routes, unsigned* __restrict__ rcnt,
    unsigned* __restrict__ glcnt, uint2* __restrict__ glist,
    unsigned* __restrict__ ovf_cnt, uint2* __restrict__ ovf)
{
  __shared__ uint2 bins[NGRP][BINCAP];   // 64*96*8 = 48KB
  __shared__ unsigned bcnt[NGRP];
  __shared__ unsigned bbase[NGRP];
  __shared__ unsigned anyf;
  const int t = threadIdx.x;
  const int lane = t & 63;
  const int wv = t >> 6;
  const int row0 = blockIdx.x * BINROWS;
  const int b = row0 / J;

  // ---- folded k_fix pre-phase (rare; scratch aliases bins LDS) ----
  if (t == 0) anyf = 0u;
  __syncthreads();
  if (t < BINROWS && flags[row0 + t]) anyf = 1u;
  __syncthreads();
  if (anyf) {
    unsigned* lsk = (unsigned*)bins;                          // [16][TOPK+1]
    unsigned short* lsi = (unsigned short*)(lsk + BINROWS * (TOPK + 1));
    float* lv = (float*)(lsi + BINROWS * TOPK);               // [16][DDIM]
    if (t < BINROWS && flags[row0 + t]) {
      const int row = row0 + t;
      unsigned* mk = lsk + t * (TOPK + 1);
      unsigned short* mi = lsi + t * TOPK;
      float* mv = lv + t * DDIM;
      for (int d = 0; d < DDIM; ++d) mv[d] = val[(size_t)row * DDIM + d];
      int m = 0, worst = 0;
      for (int k = 0; k < KDIM; ++k) {
        float acc = 0.f;
        #pragma unroll 8
        for (int d = 0; d < DDIM; ++d) acc = fmaf(mv[d], W[(size_t)d * KDIM + k], acc);
        const unsigned key = f2key(acc);
        if (m < TOPK) {
          mk[m] = key; mi[m] = (unsigned short)k; ++m;
          if (m == TOPK) {
            worst = 0;
            for (int q = 1; q < TOPK; ++q)
              if (mk[q] < mk[worst] ||
                  (mk[q] == mk[worst] && mi[q] > mi[worst])) worst = q;
          }
        } else if (key > mk[worst]) {  // tie -> keep earlier index
          mk[worst] = key; mi[worst] = (unsigned short)k;
          worst = 0;
          for (int q = 1; q < TOPK; ++q)
            if (mk[q] < mk[worst] ||
                (mk[q] == mk[worst] && mi[q] > mi[worst])) worst = q;
        }
      }
      unsigned km = mk[0];
      for (int q = 1; q < TOPK; ++q) if (mk[q] > km) km = mk[q];
      const float mx = key2f(km);
      float lsum = 0.f;
      for (int q = 0; q < TOPK; ++q) lsum += __expf(key2f(mk[q]) - mx);
      const float st = state[row];
      const float sender = st > 20.f ? st : log1pf(__expf(st));
      const float scale = sender / lsum;
      const unsigned jloc = (unsigned)(row & (J - 1));
      uint2* rrow = routes + (size_t)row * 64;
      for (int q = 0; q < TOPK; ++q) {
        const float w = __expf(key2f(mk[q]) - mx) * scale;
        rrow[q] = make_uint2(__float_as_uint(w), ((unsigned)mi[q] << 12) | jloc);
      }
      rcnt[row] = TOPK;
    }
    __syncthreads();   // routes/rcnt for fixed rows visible; bins free again
  }

  for (int i = t; i < NGRP; i += 256) bcnt[i] = 0u;
  __syncthreads();

  for (int i = t; i < BINROWS * 64; i += 256) {
    const int r = i >> 6, s = i & 63;
    unsigned n = rcnt[row0 + r]; if (n > 64u) n = 64u;
    if (s < (int)n) {
      const uint2 e = routes[(size_t)(row0 + r) * 64 + s];
      const unsigned k = e.y >> 12;
      const unsigned g = k >> 7;               // KG = 128
      const unsigned slot = atomicAdd(&bcnt[g], 1u);
      if (slot < BINCAP) bins[g][slot] = e;
      else {
        const unsigned op = atomicAdd(ovf_cnt, 1u);
        if (op < (unsigned)OVFCAP)
          ovf[op] = make_uint2(e.x, (((unsigned)b * KDIM + k) << 12) | (e.y & (J - 1)));
      }
    }
  }
  __syncthreads();

  if (t < NGRP) {
    unsigned c = bcnt[t]; if (c > BINCAP) c = BINCAP;
    bcnt[t] = c;
    bbase[t] = c ? atomicAdd(&glcnt[b * NGRP + t], c) : 0u;
  }
  __syncthreads();

  // wave wv flushes bins [wv*16, wv*16+16), lane-parallel within each bin
  for (int g = wv * 16; g < wv * 16 + 16; ++g) {
    const unsigned c = bcnt[g];
    const unsigned base = bbase[g];
    uint2* dst = glist + (size_t)(b * NGRP + g) * GLCAP;
    for (unsigned i2 = lane; i2 < c; i2 += 64) {
      const unsigned pos = base + i2;
      const uint2 e = bins[g][i2];
      if (pos < GLCAP) dst[pos] = e;
      else {
        const unsigned k = e.y >> 12;
        const unsigned op = atomicAdd(ovf_cnt, 1u);
        if (op < (unsigned)OVFCAP)
          ovf[op] = make_uint2(e.x, (((unsigned)b * KDIM + k) << 12) | (e.y & (J - 1)));
      }
    }
  }
}

// ---------------------------------------------------------------------------
// K2c: counting sort per (b,group): glist -> glist2 segmented by k.
// Emits bounded gather tasks (bk, start, len<=CH): R12/R13 lesson -- the
// gather loop must be branchless with a FIXED k per wave, and balanced.
// ---------------------------------------------------------------------------
__global__ void k_sort(const unsigned* __restrict__ glcnt, const uint2* __restrict__ glist,
                       uint2* __restrict__ glist2, unsigned* __restrict__ ntask,
                       uint2* __restrict__ tasks)
{
  __shared__ unsigned hist[KG];
  __shared__ unsigned offs[KG];
  __shared__ unsigned cur[KG];
  const int t = threadIdx.x;
  const int b = blockIdx.x >> 6;          // NGRP = 64
  const int g = blockIdx.x & (NGRP - 1);
  unsigned n = glcnt[b * NGRP + g]; if (n > (unsigned)GLCAP) n = (unsigned)GLCAP;
  const uint2* src = glist + (size_t)(b * NGRP + g) * GLCAP;
  uint2* dst = glist2 + (size_t)(b * NGRP + g) * GLCAP;

  for (int i = t; i < KG; i += 256) hist[i] = 0u;
  __syncthreads();
  for (unsigned i = t; i < n; i += 256)
    atomicAdd(&hist[(src[i].y >> 12) & (KG - 1)], 1u);
  __syncthreads();
  // inclusive Hillis-Steele scan over 128
  if (t < KG) offs[t] = hist[t];
  __syncthreads();
  for (int d = 1; d < KG; d <<= 1) {
    unsigned v = 0u;
    if (t < KG && t >= d) v = offs[t - d];
    __syncthreads();
    if (t < KG) offs[t] += v;
    __syncthreads();
  }
  if (t < KG) {
    const unsigned h = hist[t];
    const unsigned base = offs[t] - h;      // exclusive
    cur[t] = base;
    if (h) {
      const unsigned nt = (h + CH - 1) / CH;
      unsigned tbase = atomicAdd(ntask, nt);
      const unsigned bk = (unsigned)b * KDIM + (unsigned)g * KG + (unsigned)t;
      for (unsigned s = 0; s < nt && tbase + s < (unsigned)MAXTASK; ++s) {
        const unsigned st = base + s * CH;
        unsigned ln = h - s * CH; if (ln > (unsigned)CH) ln = CH;
        tasks[tbase + s] = make_uint2(bk, st | (ln << 16));
      }
    }
  }
  __syncthreads();
  for (unsigned i = t; i < n; i += 256) {
    const uint2 e = src[i];
    const unsigned p = atomicAdd(&cur[(e.y >> 12) & (KG - 1)], 1u);
    dst[p] = e;
  }
}

// ---------------------------------------------------------------------------
// K3: gather, TASK-LIST (R7 shape): one wave per task = one k's bounded
// 128-entry sub-segment; branchless ILP-4; register acc; ONE 256B atomic
// flush (out = dst via folded init). Tail waves fold the overflow list.
// ---------------------------------------------------------------------------
__global__ void k_gather(const unsigned* __restrict__ ntask,
                         const uint2* __restrict__ tasks,
                         const uint2* __restrict__ glist2,
                         const float* __restrict__ pv, const float* __restrict__ state,
                         float* __restrict__ out_state, float* __restrict__ out_val,
                         const unsigned* __restrict__ ovf_cnt,
                         const uint2* __restrict__ ovf)
{
  const unsigned wid = ((unsigned)blockIdx.x * blockDim.x + threadIdx.x) >> 6;
  const int lane = threadIdx.x & 63;
  unsigned nt = *ntask; if (nt > (unsigned)MAXTASK) nt = (unsigned)MAXTASK;
  if (wid < nt) {
    const uint2 tk = tasks[wid];
    const unsigned bk = tk.x;
    const int b = (int)(bk >> 13);            // KDIM = 8192
    const unsigned k = bk & (KDIM - 1);
    const unsigned g = k >> 7;                // KG = 128
    const unsigned st = tk.y & 0xFFFFu;
    const unsigned n = tk.y >> 16;
    const size_t jbase = (size_t)b * J;
    const uint2* lst = glist2 + (size_t)((unsigned)b * NGRP + g) * GLCAP + st;

    float a0 = 0.f, a1 = 0.f, a2 = 0.f, a3 = 0.f;
    float s0 = 0.f, s1 = 0.f, s2 = 0.f, s3 = 0.f;
    unsigned i = 0;
    for (; i + 4 <= n; i += 4) {
      const uint2 e0 = lst[i + 0], e1 = lst[i + 1], e2 = lst[i + 2], e3 = lst[i + 3];
      const float w0 = __uint_as_float(e0.x), w1 = __uint_as_float(e1.x);
      const float w2 = __uint_as_float(e2.x), w3 = __uint_as_float(e3.x);
      const unsigned j0 = e0.y & (J - 1), j1 = e1.y & (J - 1);
      const unsigned j2 = e2.y & (J - 1), j3 = e3.y & (J - 1);
      a0 = fmaf(w0, pv[(jbase + j0) * DD + lane], a0);
      a1 = fmaf(w1, pv[(jbase + j1) * DD + lane], a1);
      a2 = fmaf(w2, pv[(jbase + j2) * DD + lane], a2);
      a3 = fmaf(w3, pv[(jbase + j3) * DD + lane], a3);
      s0 = fmaf(w0, state[jbase + j0], s0); s1 = fmaf(w1, state[jbase + j1], s1);
      s2 = fmaf(w2, state[jbase + j2], s2); s3 = fmaf(w3, state[jbase + j3], s3);
    }
    for (; i < n; ++i) {
      const uint2 e = lst[i];
      const float w = __uint_as_float(e.x);
      const unsigned j = e.y & (J - 1);
      a0 = fmaf(w, pv[(jbase + j) * DD + lane], a0);
      s0 = fmaf(w, state[jbase + j], s0);
    }
    atomicAdd(&out_val[(size_t)bk * DD + lane], (a0 + a1) + (a2 + a3));
    if (lane == 0) atomicAdd(&out_state[bk], (s0 + s1) + (s2 + s3));
  }

  // ---- overflow fold (list ~always tiny; all waves grid-stride) ----
  unsigned novf = *ovf_cnt;
  if (novf > (unsigned)OVFCAP) novf = (unsigned)OVFCAP;
  const unsigned nw = ((unsigned)gridDim.x * blockDim.x) >> 6;
  for (unsigned i = wid; i < novf; i += nw) {
    const uint2 e = ovf[i];
    const float w = __uint_as_float(e.x);
    const unsigned bk = e.y >> 12;
    const unsigned j = e.y & (J - 1);
    const size_t jg = (size_t)(bk >> 13) * J + j;
    atomicAdd(&out_val[(size_t)bk * DD + lane], w * pv[jg * DD + lane]);
    if (lane == 0) atomicAdd(&out_state[bk], w * state[jg]);
  }
}

// ---------------------------------------------------------------------------
extern "C" void kernel_launch(void* const* d_in, const int* in_sizes, int n_in,
                              void* d_out, int out_size, void* d_ws, size_t ws_size,
                              hipStream_t stream)
{
  (void)in_sizes; (void)n_in; (void)out_size; (void)ws_size;
  const float* val       = (const float*)d_in[0];
  const float* state     = (const float*)d_in[1];
  const float* dst_state = (const float*)d_in[2];
  const float* dst_val   = (const float*)d_in[3];
  const float* W_route   = (const float*)d_in[4];
  const float* W_val     = (const float*)d_in[5];
  float* out_state = (float*)d_out;
  float* out_val   = out_state + (size_t)NB * KDIM;

  char* p = (char*)d_ws;
  unsigned* rcnt    = (unsigned*)p;  p += (size_t)NB * J * 4;          // 64 KB
  unsigned* flags   = (unsigned*)p;  p += (size_t)NB * J * 4;          // 64 KB
  unsigned* ovf_cnt = (unsigned*)p;  p += 256;                         // 256 B (slot 1 = ntask)
  unsigned* gcnt    = (unsigned*)p;  p += (size_t)NB * J * 2 * 4;      // 128 KB
  unsigned* glcnt   = (unsigned*)p;  p += (size_t)NB * NGRP * 4;       // 1 KB
  uint2* tasks      = (uint2*)p;     p += (size_t)MAXTASK * 8;         // 320 KB
  float* pv         = (float*)p;     p += (size_t)NB * J * DD * 4;     // 4 MB
  unsigned* WFh     = (unsigned*)p;  p += (size_t)KDIM * DDIM * 2;     // 1 MB
  float* WT         = (float*)p;     p += (size_t)KDIM * DDIM * 4;     // 2 MB
  float* gtau       = (float*)p;     p += (size_t)NB * J * 4;          // 64 KB
  unsigned short* gidx = (unsigned short*)p;                            // 8 MB
  uint2* glist2     = (uint2*)p;     p += (size_t)NB * J * GCAP * 2;   // (alias start)
  uint2* routes     = (uint2*)p;     p += (size_t)NB * J * 64 * 8;     // 8 MB
  // glist2 (16 MB) aliases gidx+routes: both dead before k_sort runs.
  uint2* glist      = (uint2*)p;     p += (size_t)NB * NGRP * GLCAP * 8; // 16 MB
  uint2* ovf        = (uint2*)p;     p += (size_t)OVFCAP * 8;          // 2 MB
  unsigned* ntask   = ovf_cnt + 1;   // inside the zeroed 256B pad

  // control-region zeroing folded into k_prep; k_fix folded into k_bin
  hipLaunchKernelGGL(k_prep, dim3(KDIM / 64 + 1024), dim3(256), 0, stream,
                     W_route, WFh, WT, dst_state, dst_val, out_state, out_val,
                     (uint4*)rcnt);
  hipLaunchKernelGGL(k_cand, dim3(NB * J / BM, 2), dim3(THREADS), 0, stream,
                     val, WFh, W_val, pv, gidx, gcnt, gtau, flags);
  hipLaunchKernelGGL(k_select, dim3(NB * J / (THREADS_SEL / 64)), dim3(THREADS_SEL),
                     0, stream, val, state, WT, gidx, gcnt, gtau, flags,
                     routes, rcnt);
  hipLaunchKernelGGL(k_bin, dim3(NB * J / BINROWS), dim3(256), 0, stream,
                     val, state, W_route, flags, routes, rcnt,
                     glcnt, glist, ovf_cnt, ovf);
  hipLaunchKernelGGL(k_sort, dim3(NB * NGRP), dim3(256), 0, stream,
                     glcnt, glist, glist2, ntask, tasks);
  hipLaunchKernelGGL(k_gather, dim3(MAXTASK / 4), dim3(256), 0, stream,
                     ntask, tasks, glist2, pv, state, out_state, out_val,
                     ovf_cnt, ovf);
}